// Round 20
// baseline (301.918 us; speedup 1.0000x reference)
//
#include <hip/hip_runtime.h>

// SpikeFFN: out = spike(LIF(x @ W1^T)) @ W2^T ; T=4 B=8 N=1024 C=512, fp32.
//
// HARD CONSTRAINT (r8): GEMM1 = single full-K ascending serial FMA chain per
// output in fp32 (np reference arithmetic); v_fma_f32 == CPU vfmadd.
// Tiling/load order free; per-output chain order is not.
//
// History: r13 (s_load B + LDS A, 2 blocks/CU) = 197us @ 66% VALU (lgkm
// drains). r14-r17 VMEM-register-ring B: spill or insufficient depth ->
// 339-5368us. Dead end at this register budget.
// r19: keep r13's fragment scheme, crank TLP to hide the drains:
//   - 64-col wave panel -> acc[4][8]=32, demand ~50 VGPR <= 64 cap
//   - __launch_bounds__(512,8): 8 waves/SIMD
//   - single-buffer LDS (33.3 KB) -> 4 blocks/CU (133 KB, 2048 thr)
//   - grid (128,8) = 1024 blocks = 4/CU exactly
// A stalled wave's lgkmcnt(0) is covered by 31 other resident waves.

typedef _Float16 half8  __attribute__((ext_vector_type(8)));
typedef _Float16 half4v __attribute__((ext_vector_type(4)));
typedef float    f32x4  __attribute__((ext_vector_type(4)));
typedef float    f32x8  __attribute__((ext_vector_type(8)));
typedef unsigned short ushort8 __attribute__((ext_vector_type(8)));

constexpr int TT   = 4;
constexpr int BB   = 8;
constexpr int NN   = 1024;
constexpr int CC   = 512;                 // Cin == Cout
constexpr int MROW = BB * NN;             // 8192 rows per timestep
constexpr int MTOT = TT * MROW;           // 32768 rows total
constexpr int BNC  = MROW * CC;           // per-timestep elems
constexpr int LDK  = 40;                  // fp16 LDS stride (gemm2)
constexpr int LTA  = 260;                 // fp32 LDS row stride (256+4 pad)

// --------------------------- W1 -> Wt[k][o] transpose ----------------------
__global__ __launch_bounds__(256)
void transpose_w(const float* __restrict__ W, float* __restrict__ Wt) {
    __shared__ float T[64][65];
    const int tid = threadIdx.x;
    const int bo  = blockIdx.x * 64;   // o tile
    const int bk  = blockIdx.y * 64;   // k tile
#pragma unroll
    for (int j = 0; j < 16; ++j) {
        int id = tid + 256 * j;
        int r = id >> 6, c = id & 63;              // r: o, c: k
        T[r][c] = W[(size_t)(bo + r) * CC + bk + c];
    }
    __syncthreads();
#pragma unroll
    for (int j = 0; j < 16; ++j) {
        int id = tid + 256 * j;
        int r = id >> 6, c = id & 63;              // r: k, c: o
        Wt[(size_t)(bk + r) * CC + bo + c] = T[c][r];
    }
}

// ---------- GEMM1: single full-K ascending serial FMA chain (fp32) ---------
// 256x64 block tile, 512 threads (8 waves x 8 cols), 4x8 outputs/thread.
// A: single-buffer LDS, k-transposed, lane reads contiguous b128.
// B: wave-uniform s_load (f32x8) from Wt (readfirstlane'd wave col base).
__global__ __launch_bounds__(512, 8)
void gemm1_v19(const float* __restrict__ X, const float* __restrict__ Wt,
               float* __restrict__ H) {
#pragma clang fp contract(off)
    __shared__ float At[32][LTA];   // 33.3 KB -> 4 blocks/CU

    const int tid  = threadIdx.x;
    const int lane = tid & 63;
    const int wid  = __builtin_amdgcn_readfirstlane(tid >> 6);  // 0..7 uniform
    const int RM   = blockIdx.x * 256;
    const int CN   = blockIdx.y * 64 + wid * 8;   // wave col base (uniform)
    const float* wcol = Wt + CN;                  // Wt[gk][CN..CN+7]

    const int srow = tid >> 1;           // staging row 0..255
    const int sk16 = (tid & 1) * 16;     // staging k base (0 or 16)

    float acc[4][8] = {};                // ONE accumulator per output
    f32x4 rx[4];                         // A staging prefetch

    // prologue: load + stage tile 0
#pragma unroll
    for (int q = 0; q < 4; ++q)
        rx[q] = *(const f32x4*)&X[(size_t)(RM + srow) * CC + sk16 + q * 4];
#pragma unroll
    for (int q = 0; q < 4; ++q)
#pragma unroll
        for (int e = 0; e < 4; ++e)
            At[sk16 + q * 4 + e][srow] = rx[q][e];
    __syncthreads();

    for (int kt = 0; kt < 16; ++kt) {
        // issue A loads for tile kt+1 (in flight during this tile's FMAs)
        if (kt < 15) {
            int kk = (kt + 1) * 32;
#pragma unroll
            for (int q = 0; q < 4; ++q)
                rx[q] = *(const f32x4*)&X[(size_t)(RM + srow) * CC + kk + sk16 + q * 4];
        }
        // FMA phase: strict ascending k; B wave-uniform scalar loads
#pragma unroll 4
        for (int k = 0; k < 32; ++k) {
            f32x8 b = *(const f32x8*)&wcol[(size_t)(kt * 32 + k) * CC];
            f32x4 a = *(const f32x4*)&At[k][lane * 4];
#pragma unroll
            for (int i = 0; i < 4; ++i)
#pragma unroll
                for (int e = 0; e < 4; ++e) {
                    acc[i][e]     = __builtin_fmaf(a[i], b[e],     acc[i][e]);
                    acc[i][4 + e] = __builtin_fmaf(a[i], b[4 + e], acc[i][4 + e]);
                }
        }
        // swap: stage tile kt+1 (single buffer -> barrier, write, barrier)
        if (kt < 15) {
            __syncthreads();
#pragma unroll
            for (int q = 0; q < 4; ++q)
#pragma unroll
                for (int e = 0; e < 4; ++e)
                    At[sk16 + q * 4 + e][srow] = rx[q][e];
            __syncthreads();
        }
    }

#pragma unroll
    for (int i = 0; i < 4; ++i) {
        size_t base = (size_t)(RM + lane * 4 + i) * CC + CN;
        f32x4 o0 = {acc[i][0], acc[i][1], acc[i][2], acc[i][3]};
        f32x4 o1 = {acc[i][4], acc[i][5], acc[i][6], acc[i][7]};
        *(f32x4*)&H[base]     = o0;
        *(f32x4*)&H[base + 4] = o1;
    }
}

// ----------------------------- LIF (fp32, np-op-exact) ---------------------
// Spike byte: 0x3C (= high byte of fp16 1.0) or 0x00.
__global__ __launch_bounds__(256)
void lif_np(const float* __restrict__ H, unsigned char* __restrict__ S8) {
#pragma clang fp contract(off)
    int g = blockIdx.x * 256 + threadIdx.x;   // 0 .. BNC/4-1
    float v[4] = {0.f, 0.f, 0.f, 0.f};
#pragma unroll
    for (int t = 0; t < TT; ++t) {
        f32x4 h = *(const f32x4*)&H[(size_t)t * BNC + (size_t)g * 4];
        unsigned int pack = 0;
#pragma unroll
        for (int e = 0; e < 4; ++e) {
            float d  = h[e] - v[e];          // rounded sub (np: x - (v-0))
            float d2 = d * 0.5f;             // exact (np: /2.0)
            v[e] = v[e] + d2;                // rounded add
            bool sp = v[e] >= 1.0f;
            if (sp) { pack |= 0x3Cu << (8 * e); v[e] = 0.0f; }
        }
        *(unsigned int*)&S8[(size_t)t * BNC + (size_t)g * 4] = pack;
    }
}

// ---------------------------------------------------------------- GEMM2 ----
// O[m][p] = sum_o S[m][o] * W2[p][o]. fp16 MFMA; spikes exact in fp16.
__global__ __launch_bounds__(256)
void gemm2_f16(const unsigned char* __restrict__ S8, const float* __restrict__ W,
               float* __restrict__ O) {
    __shared__ _Float16 As[128][LDK], Bs[128][LDK];

    const int tid  = threadIdx.x;
    const int RM   = blockIdx.x * 128;
    const int CN   = blockIdx.y * 128;
    const int lane = tid & 63;
    const int wv   = tid >> 6;
    const int wr   = (wv >> 1) * 64;
    const int wc   = (wv & 1) * 64;
    const int r15  = lane & 15;
    const int kg   = lane >> 4;

    f32x4 acc[4][4] = {};

    for (int k0 = 0; k0 < CC; k0 += 32) {
        __syncthreads();
#pragma unroll
        for (int j = 0; j < 2; ++j) {
            int id  = tid + 256 * j;
            int row = id >> 2;
            int c8  = (id & 3) * 8;
            unsigned long long v =
                *(const unsigned long long*)&S8[(size_t)(RM + row) * CC + k0 + c8];
            ushort8 u;
#pragma unroll
            for (int e = 0; e < 8; ++e)
                u[e] = (unsigned short)(((v >> (8 * e)) & 0xFFull) << 8);
            *(ushort8*)&As[row][c8] = u;
        }
#pragma unroll
        for (int j = 0; j < 4; ++j) {
            int id  = tid + 256 * j;
            int row = id >> 3;
            int c4  = (id & 7) * 4;
            f32x4 v = *(const f32x4*)&W[(size_t)(CN + row) * CC + k0 + c4];
            half4v hv;
#pragma unroll
            for (int e = 0; e < 4; ++e) hv[e] = (_Float16)v[e];
            *(half4v*)&Bs[row][c4] = hv;
        }
        __syncthreads();

        half8 a[4], b[4];
#pragma unroll
        for (int i = 0; i < 4; ++i) {
            a[i] = *(const half8*)&As[wr + i * 16 + r15][kg * 8];
            b[i] = *(const half8*)&Bs[wc + i * 16 + r15][kg * 8];
        }
#pragma unroll
        for (int i = 0; i < 4; ++i)
#pragma unroll
            for (int j = 0; j < 4; ++j)
                acc[i][j] = __builtin_amdgcn_mfma_f32_16x16x32_f16(a[i], b[j], acc[i][j], 0, 0, 0);
    }

#pragma unroll
    for (int i = 0; i < 4; ++i)
#pragma unroll
        for (int j = 0; j < 4; ++j)
#pragma unroll
            for (int r = 0; r < 4; ++r) {
                int gm = RM + wr + i * 16 + kg * 4 + r;
                int gn = CN + wc + j * 16 + r15;
                O[(size_t)gm * CC + gn] = acc[i][j][r];
            }
}

// -------------------------------------------------------------- launch -----
extern "C" void kernel_launch(void* const* d_in, const int* in_sizes, int n_in,
                              void* d_out, int out_size, void* d_ws, size_t ws_size,
                              hipStream_t stream) {
    const float* x  = (const float*)d_in[0];
    const float* W1 = (const float*)d_in[1];
    const float* W2 = (const float*)d_in[2];
    float* out = (float*)d_out;

    float*         h  = out;                                   // fp32 h in d_out
    unsigned char* s8 = (unsigned char*)d_ws;                  // spikes, 16 MB
    float*         wt = (float*)((char*)d_ws + (size_t)BNC);   // Wt, 1 MB

    dim3 gt(CC / 64, CC / 64);       // (8, 8)
    transpose_w<<<gt, 256, 0, stream>>>(W1, wt);

    dim3 g1(MTOT / 256, CC / 64);    // (128, 8) = 1024 blocks = 4/CU
    gemm1_v19<<<g1, 512, 0, stream>>>(x, wt, h);

    lif_np<<<BNC / 4 / 256, 256, 0, stream>>>(h, s8);

    dim3 g2(MTOT / 128, CC / 128);   // (256, 4)
    gemm2_f16<<<g2, 256, 0, stream>>>(s8, W2, out);
}

// Round 21
// 282.618 us; speedup vs baseline: 1.0683x; 1.0683x over previous
//
#include <hip/hip_runtime.h>

// SpikeFFN: out = spike(LIF(x @ W1^T)) @ W2^T ; T=4 B=8 N=1024 C=512, fp32.
//
// HARD CONSTRAINT (r8): GEMM1 = single full-K ascending serial FMA chain per
// output in fp32 (np reference arithmetic); v_fma_f32 == CPU vfmadd.
// Tiling/load order free; per-output chain order is not.
//
// r13 (best, 197us @66% VALU): per-k ds_read issued right before its lgkm
// drain -> ~120cyc DS latency exposed per k (OOO s_load forces drain-to-0).
// r14-r20: VMEM rings / 8-wave TLP all spill (VGPR tiers: <=64 unreachable,
// <=128 proven OK at ~90 live).
// r21: group-of-4k software pipeline, 1 group ahead, static even/odd regs:
// FMA(g) uses aA/bA loaded 256 FMA-cyc earlier; aB (4x ds_read_b128) and
// bB (4x s_load_dwordx8) for g+1 issue during FMA(g). Every lgkm item is
// old at its drain -> drains ~free. 256x64 tile, 8 waves x 8 cols,
// launch_bounds(512,4), single-buffer LDS + rx staging prefetch.

typedef _Float16 half8  __attribute__((ext_vector_type(8)));
typedef _Float16 half4v __attribute__((ext_vector_type(4)));
typedef float    f32x4  __attribute__((ext_vector_type(4)));
typedef float    f32x8  __attribute__((ext_vector_type(8)));
typedef unsigned short ushort8 __attribute__((ext_vector_type(8)));

constexpr int TT   = 4;
constexpr int BB   = 8;
constexpr int NN   = 1024;
constexpr int CC   = 512;                 // Cin == Cout
constexpr int MROW = BB * NN;             // 8192 rows per timestep
constexpr int MTOT = TT * MROW;           // 32768 rows total
constexpr int BNC  = MROW * CC;           // per-timestep elems
constexpr int LDK  = 40;                  // fp16 LDS stride (gemm2)
constexpr int LTA  = 260;                 // fp32 LDS row stride (256+4 pad)

// --------------------------- W1 -> Wt[k][o] transpose ----------------------
__global__ __launch_bounds__(256)
void transpose_w(const float* __restrict__ W, float* __restrict__ Wt) {
    __shared__ float T[64][65];
    const int tid = threadIdx.x;
    const int bo  = blockIdx.x * 64;   // o tile
    const int bk  = blockIdx.y * 64;   // k tile
#pragma unroll
    for (int j = 0; j < 16; ++j) {
        int id = tid + 256 * j;
        int r = id >> 6, c = id & 63;              // r: o, c: k
        T[r][c] = W[(size_t)(bo + r) * CC + bk + c];
    }
    __syncthreads();
#pragma unroll
    for (int j = 0; j < 16; ++j) {
        int id = tid + 256 * j;
        int r = id >> 6, c = id & 63;              // r: k, c: o
        Wt[(size_t)(bk + r) * CC + bo + c] = T[c][r];
    }
}

// ---------- GEMM1: single full-K ascending serial FMA chain (fp32) ---------
// 256x64 block tile, 512 threads (8 waves x 8 cols), 4x8 outputs/thread.
// A: single-buffer LDS (k-transposed), group-ahead ds_read into aA/aB.
// B: wave-uniform s_load from Wt, group-ahead into bA/bB (SGPR).
__global__ __launch_bounds__(512, 4)
void gemm1_v21(const float* __restrict__ X, const float* __restrict__ Wt,
               float* __restrict__ H) {
#pragma clang fp contract(off)
    __shared__ float At[32][LTA];   // 33.3 KB

    const int tid  = threadIdx.x;
    const int lane = tid & 63;
    const int wid  = __builtin_amdgcn_readfirstlane(tid >> 6);  // 0..7 uniform
    const int RM   = blockIdx.x * 256;
    const int CN   = blockIdx.y * 64 + wid * 8;   // wave col base (uniform)
    const float* wcol = Wt + CN;                  // Wt[gk][CN..CN+7]

    const int srow = tid >> 1;           // staging row 0..255
    const int sk16 = (tid & 1) * 16;     // staging k base (0 or 16)

    float acc[4][8] = {};                // ONE accumulator per output
    f32x4 rx[4];                         // A staging prefetch (VMEM)
    f32x4 aA[4], aB[4];                  // A group regs (from LDS)
    f32x8 bA[4], bB[4];                  // B group regs (SGPR via s_load)

#define LOAD_A(DST, KBASE)                                                   \
    {                                                                        \
        _Pragma("unroll")                                                    \
        for (int kk = 0; kk < 4; ++kk)                                       \
            DST[kk] = *(const f32x4*)&At[(KBASE) + kk][lane * 4];            \
    }
#define LOAD_B(DST, GROW)                                                    \
    {                                                                        \
        _Pragma("unroll")                                                    \
        for (int kk = 0; kk < 4; ++kk)                                       \
            DST[kk] = *(const f32x8*)&wcol[(size_t)((GROW) + kk) * CC];      \
    }
#define FMA_G(AR, BR)                                                        \
    {                                                                        \
        _Pragma("unroll")                                                    \
        for (int kk = 0; kk < 4; ++kk) {                                     \
            _Pragma("unroll")                                                \
            for (int i = 0; i < 4; ++i) {                                    \
                _Pragma("unroll")                                            \
                for (int e = 0; e < 4; ++e) {                                \
                    acc[i][e]     = __builtin_fmaf(AR[kk][i], BR[kk][e],     \
                                                   acc[i][e]);               \
                    acc[i][4 + e] = __builtin_fmaf(AR[kk][i], BR[kk][4 + e], \
                                                   acc[i][4 + e]);           \
                }                                                            \
            }                                                                \
        }                                                                    \
    }

    // ---- prologue: stage tile 0; preload bA (rows 0..3) ----
#pragma unroll
    for (int q = 0; q < 4; ++q)
        rx[q] = *(const f32x4*)&X[(size_t)(RM + srow) * CC + sk16 + q * 4];
#pragma unroll
    for (int q = 0; q < 4; ++q)
#pragma unroll
        for (int e = 0; e < 4; ++e)
            At[sk16 + q * 4 + e][srow] = rx[q][e];
    LOAD_B(bA, 0)
    __syncthreads();

    for (int kt = 0; kt < 16; ++kt) {
        // group-0 A regs from freshly staged LDS
        LOAD_A(aA, 0)
        // issue A staging loads for tile kt+1 (VMEM, land under this tile)
        if (kt < 15) {
            int kk = (kt + 1) * 32;
#pragma unroll
            for (int q = 0; q < 4; ++q)
                rx[q] = *(const f32x4*)&X[(size_t)(RM + srow) * CC + kk + sk16 + q * 4];
        }
        const int kb = kt * 32;
        // 8 groups of 4 k, pipelined one group ahead, even/odd static regs
#pragma unroll 1
        for (int g = 0; g < 8; g += 2) {
            // even group g: consume aA/bA; prefetch g+1 into aB/bB
            LOAD_A(aB, (g + 1) * 4)
            LOAD_B(bB, kb + (g + 1) * 4)
            FMA_G(aA, bA)
            // odd group g+1: consume aB/bB; prefetch g+2 into aA/bA
            if (g < 6) LOAD_A(aA, (g + 2) * 4)
            LOAD_B(bA, kb + (g + 2) * 4)   // g=6 -> rows kb+32 = next tile g0
            FMA_G(aB, bB)                   // (kt=15: pad rows 512..515)
        }
        // stage tile kt+1 (single buffer: barrier, write, barrier)
        if (kt < 15) {
            __syncthreads();
#pragma unroll
            for (int q = 0; q < 4; ++q)
#pragma unroll
                for (int e = 0; e < 4; ++e)
                    At[sk16 + q * 4 + e][srow] = rx[q][e];
            __syncthreads();
        }
    }
#undef LOAD_A
#undef LOAD_B
#undef FMA_G

#pragma unroll
    for (int i = 0; i < 4; ++i) {
        size_t base = (size_t)(RM + lane * 4 + i) * CC + CN;
        f32x4 o0 = {acc[i][0], acc[i][1], acc[i][2], acc[i][3]};
        f32x4 o1 = {acc[i][4], acc[i][5], acc[i][6], acc[i][7]};
        *(f32x4*)&H[base]     = o0;
        *(f32x4*)&H[base + 4] = o1;
    }
}

// ----------------------------- LIF (fp32, np-op-exact) ---------------------
// Spike byte: 0x3C (= high byte of fp16 1.0) or 0x00.
__global__ __launch_bounds__(256)
void lif_np(const float* __restrict__ H, unsigned char* __restrict__ S8) {
#pragma clang fp contract(off)
    int g = blockIdx.x * 256 + threadIdx.x;   // 0 .. BNC/4-1
    float v[4] = {0.f, 0.f, 0.f, 0.f};
#pragma unroll
    for (int t = 0; t < TT; ++t) {
        f32x4 h = *(const f32x4*)&H[(size_t)t * BNC + (size_t)g * 4];
        unsigned int pack = 0;
#pragma unroll
        for (int e = 0; e < 4; ++e) {
            float d  = h[e] - v[e];          // rounded sub (np: x - (v-0))
            float d2 = d * 0.5f;             // exact (np: /2.0)
            v[e] = v[e] + d2;                // rounded add
            bool sp = v[e] >= 1.0f;
            if (sp) { pack |= 0x3Cu << (8 * e); v[e] = 0.0f; }
        }
        *(unsigned int*)&S8[(size_t)t * BNC + (size_t)g * 4] = pack;
    }
}

// ---------------------------------------------------------------- GEMM2 ----
// O[m][p] = sum_o S[m][o] * W2[p][o]. fp16 MFMA; spikes exact in fp16.
__global__ __launch_bounds__(256)
void gemm2_f16(const unsigned char* __restrict__ S8, const float* __restrict__ W,
               float* __restrict__ O) {
    __shared__ _Float16 As[128][LDK], Bs[128][LDK];

    const int tid  = threadIdx.x;
    const int RM   = blockIdx.x * 128;
    const int CN   = blockIdx.y * 128;
    const int lane = tid & 63;
    const int wv   = tid >> 6;
    const int wr   = (wv >> 1) * 64;
    const int wc   = (wv & 1) * 64;
    const int r15  = lane & 15;
    const int kg   = lane >> 4;

    f32x4 acc[4][4] = {};

    for (int k0 = 0; k0 < CC; k0 += 32) {
        __syncthreads();
#pragma unroll
        for (int j = 0; j < 2; ++j) {
            int id  = tid + 256 * j;
            int row = id >> 2;
            int c8  = (id & 3) * 8;
            unsigned long long v =
                *(const unsigned long long*)&S8[(size_t)(RM + row) * CC + k0 + c8];
            ushort8 u;
#pragma unroll
            for (int e = 0; e < 8; ++e)
                u[e] = (unsigned short)(((v >> (8 * e)) & 0xFFull) << 8);
            *(ushort8*)&As[row][c8] = u;
        }
#pragma unroll
        for (int j = 0; j < 4; ++j) {
            int id  = tid + 256 * j;
            int row = id >> 3;
            int c4  = (id & 7) * 4;
            f32x4 v = *(const f32x4*)&W[(size_t)(CN + row) * CC + k0 + c4];
            half4v hv;
#pragma unroll
            for (int e = 0; e < 4; ++e) hv[e] = (_Float16)v[e];
            *(half4v*)&Bs[row][c4] = hv;
        }
        __syncthreads();

        half8 a[4], b[4];
#pragma unroll
        for (int i = 0; i < 4; ++i) {
            a[i] = *(const half8*)&As[wr + i * 16 + r15][kg * 8];
            b[i] = *(const half8*)&Bs[wc + i * 16 + r15][kg * 8];
        }
#pragma unroll
        for (int i = 0; i < 4; ++i)
#pragma unroll
            for (int j = 0; j < 4; ++j)
                acc[i][j] = __builtin_amdgcn_mfma_f32_16x16x32_f16(a[i], b[j], acc[i][j], 0, 0, 0);
    }

#pragma unroll
    for (int i = 0; i < 4; ++i)
#pragma unroll
        for (int j = 0; j < 4; ++j)
#pragma unroll
            for (int r = 0; r < 4; ++r) {
                int gm = RM + wr + i * 16 + kg * 4 + r;
                int gn = CN + wc + j * 16 + r15;
                O[(size_t)gm * CC + gn] = acc[i][j][r];
            }
}

// -------------------------------------------------------------- launch -----
extern "C" void kernel_launch(void* const* d_in, const int* in_sizes, int n_in,
                              void* d_out, int out_size, void* d_ws, size_t ws_size,
                              hipStream_t stream) {
    const float* x  = (const float*)d_in[0];
    const float* W1 = (const float*)d_in[1];
    const float* W2 = (const float*)d_in[2];
    float* out = (float*)d_out;

    float*         h  = out;                                   // fp32 h in d_out
    unsigned char* s8 = (unsigned char*)d_ws;                  // spikes, 16 MB
    float*         wt = (float*)((char*)d_ws + (size_t)BNC);   // Wt, 512+4 rows

    dim3 gt(CC / 64, CC / 64);       // (8, 8)
    transpose_w<<<gt, 256, 0, stream>>>(W1, wt);

    dim3 g1(MTOT / 256, CC / 64);    // (128, 8) = 1024 blocks
    gemm1_v21<<<g1, 512, 0, stream>>>(x, wt, h);

    lif_np<<<BNC / 4 / 256, 256, 0, stream>>>(h, s8);

    dim3 g2(MTOT / 128, CC / 128);   // (256, 4)
    gemm2_f16<<<g2, 256, 0, stream>>>(s8, W2, out);
}

// Round 22
// 253.314 us; speedup vs baseline: 1.1919x; 1.1157x over previous
//
#include <hip/hip_runtime.h>

// SpikeFFN: out = spike(LIF(x @ W1^T)) @ W2^T ; T=4 B=8 N=1024 C=512, fp32.
//
// HARD CONSTRAINT (r8): GEMM1 = single full-K ascending serial FMA chain per
// output in fp32 (np reference arithmetic); v_fma_f32 == CPU vfmadd.
// Tiling/load order free; per-output chain order is not.
//
// Register-tier map (measured r13-r21): <=64-VGPR tier needs <=~45 live
// floats (r19's ~60 spilled); 128-tier needs <=~60 (r21's ~90 spilled).
// r13 (2r13-blocks/CU, 4 waves/SIMD, 56 VGPR) = 197us @ 66% VALU, stalled
// on per-k lgkmcnt(0) drains (OOO s_load) -- only MORE WAVES can hide them.
// r22: fit the 8-waves/SIMD tier with margin: spatial 2x8 (acc 16),
// demand ~36 VGPR. 128x64 block, 512 thr, dbuf LDS 33.3KB -> 4 blocks/CU,
// 32 waves/CU. B: wave-uniform s_load f32x8 (r13-proven); A: ds_read_b64.

typedef _Float16 half8  __attribute__((ext_vector_type(8)));
typedef _Float16 half4v __attribute__((ext_vector_type(4)));
typedef float    f32x2  __attribute__((ext_vector_type(2)));
typedef float    f32x4  __attribute__((ext_vector_type(4)));
typedef float    f32x8  __attribute__((ext_vector_type(8)));
typedef unsigned short ushort8 __attribute__((ext_vector_type(8)));

constexpr int TT   = 4;
constexpr int BB   = 8;
constexpr int NN   = 1024;
constexpr int CC   = 512;                 // Cin == Cout
constexpr int MROW = BB * NN;             // 8192 rows per timestep
constexpr int MTOT = TT * MROW;           // 32768 rows total
constexpr int BNC  = MROW * CC;           // per-timestep elems
constexpr int LDK  = 40;                  // fp16 LDS stride (gemm2)
constexpr int LTA2 = 130;                 // fp32 LDS row stride (128+2)

// --------------------------- W1 -> Wt[k][o] transpose ----------------------
__global__ __launch_bounds__(256)
void transpose_w(const float* __restrict__ W, float* __restrict__ Wt) {
    __shared__ float T[64][65];
    const int tid = threadIdx.x;
    const int bo  = blockIdx.x * 64;   // o tile
    const int bk  = blockIdx.y * 64;   // k tile
#pragma unroll
    for (int j = 0; j < 16; ++j) {
        int id = tid + 256 * j;
        int r = id >> 6, c = id & 63;              // r: o, c: k
        T[r][c] = W[(size_t)(bo + r) * CC + bk + c];
    }
    __syncthreads();
#pragma unroll
    for (int j = 0; j < 16; ++j) {
        int id = tid + 256 * j;
        int r = id >> 6, c = id & 63;              // r: k, c: o
        Wt[(size_t)(bk + r) * CC + bo + c] = T[c][r];
    }
}

// ---------- GEMM1: single full-K ascending serial FMA chain (fp32) ---------
// 128x64 block tile, 512 threads (8 waves x 8 cols), 2x8 outputs/thread.
// A: double-buffered LDS (k-transposed), lane reads f32x2 (conflict-free).
// B: wave-uniform s_load f32x8 from Wt. 8 waves/SIMD hide the lgkm drains.
__global__ __launch_bounds__(512, 8)
void gemm1_v22(const float* __restrict__ X, const float* __restrict__ Wt,
               float* __restrict__ H) {
#pragma clang fp contract(off)
    __shared__ float At[2][32][LTA2];   // 33.3 KB -> 4 blocks/CU

    const int tid  = threadIdx.x;
    const int lane = tid & 63;
    const int wid  = __builtin_amdgcn_readfirstlane(tid >> 6);  // 0..7 uniform
    const int RM   = blockIdx.x * 128;
    const int CN   = blockIdx.y * 64 + wid * 8;   // wave col base (uniform)
    const float* wcol = Wt + CN;                  // Wt[gk][CN..CN+7]

    const int srow = tid >> 2;           // staging row 0..127
    const int sk8  = (tid & 3) * 8;      // staging k base 0,8,16,24

    float acc[2][8] = {};                // ONE accumulator per output (16)
    f32x4 rx0, rx1;                      // A staging prefetch (8)

    // prologue: load + stage tile 0
    rx0 = *(const f32x4*)&X[(size_t)(RM + srow) * CC + sk8];
    rx1 = *(const f32x4*)&X[(size_t)(RM + srow) * CC + sk8 + 4];
#pragma unroll
    for (int e = 0; e < 4; ++e) {
        At[0][sk8 + e][srow]     = rx0[e];
        At[0][sk8 + 4 + e][srow] = rx1[e];
    }
    __syncthreads();

    for (int kt = 0; kt < 16; ++kt) {
        const int cur = kt & 1;
        // issue A loads for tile kt+1 (in flight during this tile's FMAs)
        if (kt < 15) {
            int kk = (kt + 1) * 32;
            rx0 = *(const f32x4*)&X[(size_t)(RM + srow) * CC + kk + sk8];
            rx1 = *(const f32x4*)&X[(size_t)(RM + srow) * CC + kk + sk8 + 4];
        }
        // FMA phase: strict ascending k; B wave-uniform s_load per k
#pragma unroll 4
        for (int k = 0; k < 32; ++k) {
            f32x8 b = *(const f32x8*)&wcol[(size_t)(kt * 32 + k) * CC];
            f32x2 a = *(const f32x2*)&At[cur][k][lane * 2];
#pragma unroll
            for (int i = 0; i < 2; ++i)
#pragma unroll
                for (int e = 0; e < 4; ++e) {
                    acc[i][e]     = __builtin_fmaf(a[i], b[e],     acc[i][e]);
                    acc[i][4 + e] = __builtin_fmaf(a[i], b[4 + e], acc[i][4 + e]);
                }
        }
        // stage tile kt+1 into the other buffer; ONE barrier per tile
        if (kt < 15) {
#pragma unroll
            for (int e = 0; e < 4; ++e) {
                At[cur ^ 1][sk8 + e][srow]     = rx0[e];
                At[cur ^ 1][sk8 + 4 + e][srow] = rx1[e];
            }
            __syncthreads();
        }
    }

#pragma unroll
    for (int i = 0; i < 2; ++i) {
        size_t base = (size_t)(RM + lane * 2 + i) * CC + CN;
        f32x4 o0 = {acc[i][0], acc[i][1], acc[i][2], acc[i][3]};
        f32x4 o1 = {acc[i][4], acc[i][5], acc[i][6], acc[i][7]};
        *(f32x4*)&H[base]     = o0;
        *(f32x4*)&H[base + 4] = o1;
    }
}

// ----------------------------- LIF (fp32, np-op-exact) ---------------------
// Spike byte: 0x3C (= high byte of fp16 1.0) or 0x00.
__global__ __launch_bounds__(256)
void lif_np(const float* __restrict__ H, unsigned char* __restrict__ S8) {
#pragma clang fp contract(off)
    int g = blockIdx.x * 256 + threadIdx.x;   // 0 .. BNC/4-1
    float v[4] = {0.f, 0.f, 0.f, 0.f};
#pragma unroll
    for (int t = 0; t < TT; ++t) {
        f32x4 h = *(const f32x4*)&H[(size_t)t * BNC + (size_t)g * 4];
        unsigned int pack = 0;
#pragma unroll
        for (int e = 0; e < 4; ++e) {
            float d  = h[e] - v[e];          // rounded sub (np: x - (v-0))
            float d2 = d * 0.5f;             // exact (np: /2.0)
            v[e] = v[e] + d2;                // rounded add
            bool sp = v[e] >= 1.0f;
            if (sp) { pack |= 0x3Cu << (8 * e); v[e] = 0.0f; }
        }
        *(unsigned int*)&S8[(size_t)t * BNC + (size_t)g * 4] = pack;
    }
}

// ---------------------------------------------------------------- GEMM2 ----
// O[m][p] = sum_o S[m][o] * W2[p][o]. fp16 MFMA; spikes exact in fp16.
__global__ __launch_bounds__(256)
void gemm2_f16(const unsigned char* __restrict__ S8, const float* __restrict__ W,
               float* __restrict__ O) {
    __shared__ _Float16 As[128][LDK], Bs[128][LDK];

    const int tid  = threadIdx.x;
    const int RM   = blockIdx.x * 128;
    const int CN   = blockIdx.y * 128;
    const int lane = tid & 63;
    const int wv   = tid >> 6;
    const int wr   = (wv >> 1) * 64;
    const int wc   = (wv & 1) * 64;
    const int r15  = lane & 15;
    const int kg   = lane >> 4;

    f32x4 acc[4][4] = {};

    for (int k0 = 0; k0 < CC; k0 += 32) {
        __syncthreads();
#pragma unroll
        for (int j = 0; j < 2; ++j) {
            int id  = tid + 256 * j;
            int row = id >> 2;
            int c8  = (id & 3) * 8;
            unsigned long long v =
                *(const unsigned long long*)&S8[(size_t)(RM + row) * CC + k0 + c8];
            ushort8 u;
#pragma unroll
            for (int e = 0; e < 8; ++e)
                u[e] = (unsigned short)(((v >> (8 * e)) & 0xFFull) << 8);
            *(ushort8*)&As[row][c8] = u;
        }
#pragma unroll
        for (int j = 0; j < 4; ++j) {
            int id  = tid + 256 * j;
            int row = id >> 3;
            int c4  = (id & 7) * 4;
            f32x4 v = *(const f32x4*)&W[(size_t)(CN + row) * CC + k0 + c4];
            half4v hv;
#pragma unroll
            for (int e = 0; e < 4; ++e) hv[e] = (_Float16)v[e];
            *(half4v*)&Bs[row][c4] = hv;
        }
        __syncthreads();

        half8 a[4], b[4];
#pragma unroll
        for (int i = 0; i < 4; ++i) {
            a[i] = *(const half8*)&As[wr + i * 16 + r15][kg * 8];
            b[i] = *(const half8*)&Bs[wc + i * 16 + r15][kg * 8];
        }
#pragma unroll
        for (int i = 0; i < 4; ++i)
#pragma unroll
            for (int j = 0; j < 4; ++j)
                acc[i][j] = __builtin_amdgcn_mfma_f32_16x16x32_f16(a[i], b[j], acc[i][j], 0, 0, 0);
    }

#pragma unroll
    for (int i = 0; i < 4; ++i)
#pragma unroll
        for (int j = 0; j < 4; ++j)
#pragma unroll
            for (int r = 0; r < 4; ++r) {
                int gm = RM + wr + i * 16 + kg * 4 + r;
                int gn = CN + wc + j * 16 + r15;
                O[(size_t)gm * CC + gn] = acc[i][j][r];
            }
}

// -------------------------------------------------------------- launch -----
extern "C" void kernel_launch(void* const* d_in, const int* in_sizes, int n_in,
                              void* d_out, int out_size, void* d_ws, size_t ws_size,
                              hipStream_t stream) {
    const float* x  = (const float*)d_in[0];
    const float* W1 = (const float*)d_in[1];
    const float* W2 = (const float*)d_in[2];
    float* out = (float*)d_out;

    float*         h  = out;                                   // fp32 h in d_out
    unsigned char* s8 = (unsigned char*)d_ws;                  // spikes, 16 MB
    float*         wt = (float*)((char*)d_ws + (size_t)BNC);   // Wt, 1 MB

    dim3 gt(CC / 64, CC / 64);       // (8, 8)
    transpose_w<<<gt, 256, 0, stream>>>(W1, wt);

    dim3 g1(MTOT / 128, CC / 64);    // (256, 8) = 2048 blocks = 8 rounds/CU
    gemm1_v22<<<g1, 512, 0, stream>>>(x, wt, h);

    lif_np<<<BNC / 4 / 256, 256, 0, stream>>>(h, s8);

    dim3 g2(MTOT / 128, CC / 128);   // (256, 4)
    gemm2_f16<<<g2, 256, 0, stream>>>(s8, W2, out);
}